// Round 12
// baseline (158.952 us; speedup 1.0000x reference)
//
#include <hip/hip_runtime.h>

#define G_ 100
#define T_ 24
#define GP1 101
#define TILE (G_ * T_)        // 2400 floats per (b,pass) tile
#define VPB (TILE / 4)        // 600 float4 per tile
#define WPB 4                 // waves per block: 2 b's x 2 passes
#define BLOCK (64 * WPB)
#define PRE 48                // ranks prefetched unconditionally (always real gens)

typedef float vfloat4 __attribute__((ext_vector_type(4)));

// One block, once: prices + stable rank-sort (== jnp.argsort) into workspace.
// Slack price (voll/vosp) > any gen price, so rank 100 is always the slack.
__global__ void setup_sort_kernel(const float* __restrict__ b_G,
                                  const float* __restrict__ voll,
                                  const float* __restrict__ vosp,
                                  const float* __restrict__ ru,
                                  const float* __restrict__ rd,
                                  int* __restrict__ order_out,     // [2][101]
                                  float* __restrict__ price_out)   // [2][101]
{
    __shared__ float pu[GP1], pd[GP1];
    int i = threadIdx.x;
    if (i < GP1) {
        if (i < G_) { float bg = b_G[i]; pu[i] = ru[0] * bg; pd[i] = rd[0] * bg; }
        else        { pu[i] = voll[0];   pd[i] = vosp[0]; }
    }
    __syncthreads();
    if (i < GP1) {
        float mu = pu[i], md = pd[i];
        int r0 = 0, r1 = 0;
        for (int j = 0; j < GP1; ++j) {
            float vu = pu[j], vd = pd[j];
            r0 += (vu < mu) || (vu == mu && j < i);
            r1 += (vd < md) || (vd == md && j < i);
        }
        order_out[r0] = i;        price_out[r0] = mu;
        order_out[GP1 + r1] = i;  price_out[GP1 + r1] = md;
    }
}

// Fallback merit-order chunk (rare tail): batch N scattered cap loads, scan,
// allocs into the wave-private LDS tile column. ord/price rank-indexed (s_load).
template<int N>
__device__ __forceinline__ void scan_chunk(int k0,
    const float* __restrict__ capp,
    const int* __restrict__ ordp, const float* __restrict__ prp,
    float* __restrict__ ldscol,
    float dem, float& before, float& objp)
{
    int gg[N]; float pr[N], cap[N];
#pragma unroll
    for (int j = 0; j < N; ++j) { gg[j] = ordp[k0 + j]; pr[j] = prp[k0 + j]; }
#pragma unroll
    for (int j = 0; j < N; ++j) cap[j] = capp[gg[j] * T_];
#pragma unroll
    for (int j = 0; j < N; ++j) {
        float a = fminf(fmaxf(dem - before, 0.f), cap[j]);
        before += cap[j];
        objp = fmaf(pr[j], a, objp);
        ldscol[gg[j] * T_] = a;
    }
}

__global__ __launch_bounds__(BLOCK, 4) void dispatch_kernel(
    const float* __restrict__ R_up, const float* __restrict__ R_dn,
    const float* __restrict__ omega,
    const int* __restrict__ ord_ws, const float* __restrict__ pr_ws,
    float* __restrict__ out, int B)
{
    __shared__ float s_tile[WPB * TILE];     // 38400 B -> 4 blocks/CU, 16 tiles
    __shared__ float s_obj[WPB];

    const int tid  = threadIdx.x;
    const int w    = tid >> 6;
    const int lane = tid & 63;
    const int b = __builtin_amdgcn_readfirstlane(blockIdx.x * 2 + (w >> 1));
    const int p = __builtin_amdgcn_readfirstlane(w & 1);
    const size_t bgt = (size_t)B * TILE;
    float* __restrict__ tw = &s_tile[w * TILE];   // wave-private tile

    const int t = (lane < T_) ? lane : 0;
    const int*   __restrict__ ordp = ord_ws + p * GP1;
    const float* __restrict__ prp  = pr_ws  + p * GP1;
    const float* __restrict__ capp = (p ? R_dn : R_up) + (size_t)b * TILE + t;

    // ---- PREFETCH: ranks 0..47 known at entry -> one 48-load window issued
    //      immediately; latency hides under LDS zeroing + omega load ----
    int   g48[PRE];
    float c48[PRE];
#pragma unroll
    for (int j = 0; j < PRE; ++j) g48[j] = ordp[j];          // uniform -> s_load
    if (lane < T_) {
#pragma unroll
        for (int j = 0; j < PRE; ++j) c48[j] = capp[g48[j] * T_];
    }
    float om = 0.f;
    if (lane < T_) om = omega[(size_t)b * T_ + t];

    // ---- zero the LDS tile: untouched merit rows must be exactly 0 ----
#pragma unroll
    for (int j = 0; j < 9; ++j) *(vfloat4*)&tw[(lane + j * 64) * 4] = (vfloat4)(0.f);
    if (lane < VPB - 576)       *(vfloat4*)&tw[(lane + 576) * 4]    = (vfloat4)(0.f);

    // ---- merit-order scan: first 48 ranks straight from registers ----
    float objp = 0.f;
    if (lane < T_) {
        const float dem = p ? fmaxf(-om, 0.f) : fmaxf(om, 0.f);
        float* __restrict__ ldscol = tw + t;

        float before = 0.f;
#pragma unroll
        for (int j = 0; j < PRE; ++j) {
            float a = fminf(fmaxf(dem - before, 0.f), c48[j]);
            before += c48[j];
            objp = fmaf(prp[j], a, objp);
            ldscol[g48[j] * T_] = a;
        }

        // rare tail: sum of 48 U[0,1] caps (~24) almost always >= dem
        bool run = __any(before < dem);
        if (run) { scan_chunk<8>(48, capp, ordp, prp, ldscol, dem, before, objp);
                   run = __any(before < dem); }
        if (run) { scan_chunk<8>(56, capp, ordp, prp, ldscol, dem, before, objp);
                   run = __any(before < dem); }
        if (run) { scan_chunk<8>(64, capp, ordp, prp, ldscol, dem, before, objp);
                   run = __any(before < dem); }
        if (run) { scan_chunk<8>(72, capp, ordp, prp, ldscol, dem, before, objp);
                   run = __any(before < dem); }
        if (run) { scan_chunk<8>(80, capp, ordp, prp, ldscol, dem, before, objp);
                   run = __any(before < dem); }
        if (run) { scan_chunk<8>(88, capp, ordp, prp, ldscol, dem, before, objp);
                   run = __any(before < dem); }
        if (run)   scan_chunk<4>(96, capp, ordp, prp, ldscol, dem, before, objp);

        // slack (rank 100): clip(dem - sum_all, 0, dem); early exit => 0.
        float slackv = fmaxf(dem - before, 0.f);
        objp = fmaf(prp[GP1 - 1], slackv, objp);
        out[2 * bgt + (size_t)p * B * T_ + (size_t)b * T_ + t] = slackv;
    }

    // ---- rt_obj partial: butterfly over the wave (idle lanes hold 0) ----
#pragma unroll
    for (int off = 32; off; off >>= 1) objp += __shfl_xor(objp, off, 64);
    if (lane == 0) s_obj[w] = objp;

    // ---- stream the finished tile out: coalesced plain float4 ----
    __builtin_amdgcn_wave_barrier();         // pin ds_write -> ds_read order
    {
        vfloat4* __restrict__ dst = (vfloat4*)out + ((size_t)p * B + b) * VPB;
#pragma unroll
        for (int j = 0; j < 9; ++j)
            dst[lane + j * 64] = *(const vfloat4*)&tw[(lane + j * 64) * 4];
        if (lane < VPB - 576)
            dst[lane + 576] = *(const vfloat4*)&tw[(lane + 576) * 4];
    }

    // ---- pair up+dn partials per b (barrier hides under stream-out) ----
    __syncthreads();
    if (tid == 0)
        out[2 * bgt + 2 * (size_t)B * T_ + b] = s_obj[0] + s_obj[1];
    if (tid == 128)
        out[2 * bgt + 2 * (size_t)B * T_ + b] = s_obj[2] + s_obj[3];
}

extern "C" void kernel_launch(void* const* d_in, const int* in_sizes, int n_in,
                              void* d_out, int out_size, void* d_ws, size_t ws_size,
                              hipStream_t stream)
{
    const float* R_up  = (const float*)d_in[0];
    const float* R_dn  = (const float*)d_in[1];
    const float* omega = (const float*)d_in[2];
    const float* b_G   = (const float*)d_in[3];
    const float* voll  = (const float*)d_in[4];
    const float* vosp  = (const float*)d_in[5];
    const float* ru    = (const float*)d_in[6];
    const float* rd    = (const float*)d_in[7];

    const int B = in_sizes[0] / TILE;
    float* out = (float*)d_out;

    int*   ord_ws = (int*)d_ws;
    float* pr_ws  = (float*)((char*)d_ws + 2 * GP1 * sizeof(int));

    setup_sort_kernel<<<1, 128, 0, stream>>>(b_G, voll, vosp, ru, rd, ord_ws, pr_ws);

    // 4 waves/block = 2 b's x 2 passes; grid B/2
    dispatch_kernel<<<B / 2, BLOCK, 0, stream>>>(
        R_up, R_dn, omega, ord_ws, pr_ws, out, B);
}

// Round 13
// 152.215 us; speedup vs baseline: 1.0443x; 1.0443x over previous
//
#include <hip/hip_runtime.h>

#define G_ 100
#define T_ 24
#define GP1 101
#define TILE (G_ * T_)        // 2400 floats per (b,pass) tile
#define VPB (TILE / 4)        // 600 float4 per tile
#define WPB 4                 // waves per block: 2 b's x 2 passes
#define BLOCK (64 * WPB)

typedef float vfloat4 __attribute__((ext_vector_type(4)));

// One block, once: prices + stable rank-sort (== jnp.argsort) into workspace.
// Slack price (voll/vosp) > any gen price, so rank 100 is always the slack.
__global__ void setup_sort_kernel(const float* __restrict__ b_G,
                                  const float* __restrict__ voll,
                                  const float* __restrict__ vosp,
                                  const float* __restrict__ ru,
                                  const float* __restrict__ rd,
                                  int* __restrict__ order_out,     // [2][101]
                                  float* __restrict__ price_out)   // [2][101]
{
    __shared__ float pu[GP1], pd[GP1];
    int i = threadIdx.x;
    if (i < GP1) {
        if (i < G_) { float bg = b_G[i]; pu[i] = ru[0] * bg; pd[i] = rd[0] * bg; }
        else        { pu[i] = voll[0];   pd[i] = vosp[0]; }
    }
    __syncthreads();
    if (i < GP1) {
        float mu = pu[i], md = pd[i];
        int r0 = 0, r1 = 0;
        for (int j = 0; j < GP1; ++j) {
            float vu = pu[j], vd = pd[j];
            r0 += (vu < mu) || (vu == mu && j < i);
            r1 += (vd < md) || (vd == md && j < i);
        }
        order_out[r0] = i;        price_out[r0] = mu;
        order_out[GP1 + r1] = i;  price_out[GP1 + r1] = md;
    }
}

// Merit-order chunk: batch N scattered 96B-row cap loads from global (L3-warm),
// serial clip-scan, allocs written to the wave-private LDS tile column.
// ord/price are rank-indexed uniform loads (SGPR, L1-hot workspace).
template<int N>
__device__ __forceinline__ void scan_chunk(int k0,
    const float* __restrict__ capp,          // R_p[b] + t (per-lane)
    const int* __restrict__ ordp, const float* __restrict__ prp,
    float* __restrict__ ldscol,              // tw + t
    float dem, float& before, float& objp)
{
    int gg[N]; float pr[N], cap[N];
#pragma unroll
    for (int j = 0; j < N; ++j) { gg[j] = ordp[k0 + j]; pr[j] = prp[k0 + j]; }
#pragma unroll
    for (int j = 0; j < N; ++j) cap[j] = capp[gg[j] * T_];   // N loads in flight
#pragma unroll
    for (int j = 0; j < N; ++j) {
        float a = fminf(fmaxf(dem - before, 0.f), cap[j]);
        before += cap[j];
        objp = fmaf(pr[j], a, objp);
        ldscol[gg[j] * T_] = a;              // ds_write, own column
    }
}

__global__ __launch_bounds__(BLOCK, 4) void dispatch_kernel(
    const float* __restrict__ R_up, const float* __restrict__ R_dn,
    const float* __restrict__ omega,
    const int* __restrict__ ord_ws, const float* __restrict__ pr_ws,
    float* __restrict__ out, int B)
{
    __shared__ float s_tile[WPB * TILE];     // 38400 B -> 4 blocks/CU, 16 tiles
    __shared__ float s_obj[WPB];

    const int tid  = threadIdx.x;
    const int w    = tid >> 6;
    const int lane = tid & 63;
    const int b = __builtin_amdgcn_readfirstlane(blockIdx.x * 2 + (w >> 1));
    const int p = __builtin_amdgcn_readfirstlane(w & 1);
    const size_t bgt = (size_t)B * TILE;
    float* __restrict__ tw = &s_tile[w * TILE];   // wave-private tile

    // ---- zero the LDS tile: untouched merit rows must be exactly 0 ----
#pragma unroll
    for (int j = 0; j < 9; ++j) *(vfloat4*)&tw[(lane + j * 64) * 4] = (vfloat4)(0.f);
    if (lane < VPB - 576)       *(vfloat4*)&tw[(lane + 576) * 4]    = (vfloat4)(0.f);

    const int t = (lane < T_) ? lane : 0;    // scan lanes: 0..23
    const int*   __restrict__ ordp = ord_ws + p * GP1;
    const float* __restrict__ prp  = pr_ws  + p * GP1;

    float objp = 0.f;
    if (lane < T_) {
        const float om  = omega[(size_t)b * T_ + t];
        const float dem = p ? fmaxf(-om, 0.f) : fmaxf(om, 0.f);
        const float* __restrict__ capp = (p ? R_dn : R_up) + (size_t)b * TILE + t;
        float* __restrict__ ldscol = tw + t;

        float before = 0.f;
        // front-loaded 16-wide chunks cover typical k* (~25-35) in 2 windows;
        // 8-wide ballot chunks catch the tail; slack handled analytically.
        scan_chunk<16>( 0, capp, ordp, prp, ldscol, dem, before, objp);
        bool run = __any(before < dem);
        if (run) { scan_chunk<16>(16, capp, ordp, prp, ldscol, dem, before, objp);
                   run = __any(before < dem); }
        if (run) { scan_chunk< 8>(32, capp, ordp, prp, ldscol, dem, before, objp);
                   run = __any(before < dem); }
        if (run) { scan_chunk< 8>(40, capp, ordp, prp, ldscol, dem, before, objp);
                   run = __any(before < dem); }
        if (run) { scan_chunk< 8>(48, capp, ordp, prp, ldscol, dem, before, objp);
                   run = __any(before < dem); }
        if (run) { scan_chunk< 8>(56, capp, ordp, prp, ldscol, dem, before, objp);
                   run = __any(before < dem); }
        if (run) { scan_chunk< 8>(64, capp, ordp, prp, ldscol, dem, before, objp);
                   run = __any(before < dem); }
        if (run) { scan_chunk< 8>(72, capp, ordp, prp, ldscol, dem, before, objp);
                   run = __any(before < dem); }
        if (run) { scan_chunk< 8>(80, capp, ordp, prp, ldscol, dem, before, objp);
                   run = __any(before < dem); }
        if (run) { scan_chunk< 8>(88, capp, ordp, prp, ldscol, dem, before, objp);
                   run = __any(before < dem); }
        if (run)   scan_chunk< 4>(96, capp, ordp, prp, ldscol, dem, before, objp);

        // slack (rank 100): clip(dem - sum_all, 0, dem); early exit => 0.
        float slackv = fmaxf(dem - before, 0.f);
        objp = fmaf(prp[GP1 - 1], slackv, objp);
        out[2 * bgt + (size_t)p * B * T_ + (size_t)b * T_ + t] = slackv;
    }

    // ---- rt_obj partial: butterfly over the wave (idle lanes hold 0) ----
#pragma unroll
    for (int off = 32; off; off >>= 1) objp += __shfl_xor(objp, off, 64);
    if (lane == 0) s_obj[w] = objp;

    // ---- stream the finished tile out: coalesced plain float4 (6.6 TB/s path)
    __builtin_amdgcn_wave_barrier();         // pin ds_write -> ds_read order
    {
        vfloat4* __restrict__ dst = (vfloat4*)out + ((size_t)p * B + b) * VPB;
#pragma unroll
        for (int j = 0; j < 9; ++j)
            dst[lane + j * 64] = *(const vfloat4*)&tw[(lane + j * 64) * 4];
        if (lane < VPB - 576)
            dst[lane + 576] = *(const vfloat4*)&tw[(lane + 576) * 4];
    }

    // ---- pair up+dn partials per b (barrier hides under stream-out) ----
    __syncthreads();
    if (tid == 0)
        out[2 * bgt + 2 * (size_t)B * T_ + b] = s_obj[0] + s_obj[1];
    if (tid == 128)
        out[2 * bgt + 2 * (size_t)B * T_ + b] = s_obj[2] + s_obj[3];
}

extern "C" void kernel_launch(void* const* d_in, const int* in_sizes, int n_in,
                              void* d_out, int out_size, void* d_ws, size_t ws_size,
                              hipStream_t stream)
{
    const float* R_up  = (const float*)d_in[0];
    const float* R_dn  = (const float*)d_in[1];
    const float* omega = (const float*)d_in[2];
    const float* b_G   = (const float*)d_in[3];
    const float* voll  = (const float*)d_in[4];
    const float* vosp  = (const float*)d_in[5];
    const float* ru    = (const float*)d_in[6];
    const float* rd    = (const float*)d_in[7];

    const int B = in_sizes[0] / TILE;
    float* out = (float*)d_out;

    int*   ord_ws = (int*)d_ws;
    float* pr_ws  = (float*)((char*)d_ws + 2 * GP1 * sizeof(int));

    setup_sort_kernel<<<1, 128, 0, stream>>>(b_G, voll, vosp, ru, rd, ord_ws, pr_ws);

    // 4 waves/block = 2 b's x 2 passes; grid B/2
    dispatch_kernel<<<B / 2, BLOCK, 0, stream>>>(
        R_up, R_dn, omega, ord_ws, pr_ws, out, B);
}